// Round 5
// baseline (326.759 us; speedup 1.0000x reference)
//
#include <hip/hip_runtime.h>
#include <cmath>
#include <complex>

namespace {

constexpr int TLEN   = 65536;
constexpr int NCH    = 512;          // 32*16 channels
constexpr int YPITCH = 65600;        // yb row pitch (floats); rows 64B-aligned

// yb layout: ROW-MAJOR yb[ch][e], e = 0..65589 (+2 garbage pad), pitch 65600.
// Each lane owns one channel; loads/stores are 16B/lane, 4 consecutive instrs
// cover one full 64B line per lane -> full line utilization, no LDS needed.

struct Coefs {
  float b0,b1,b2,b3,b4,b5,b6,b7,b8;
  float na1,na2,na3,na4,na5,na6,na7,na8;   // -a[1..8]
  float zi0,zi1,zi2,zi3,zi4,zi5,zi6,zi7;
};

#define IIR_STEP(xv, yv)                                  \
  do {                                                    \
    yv = fmaf(cf.b0, (xv), z0);                           \
    z0 = fmaf(cf.na1, yv, fmaf(cf.b1, (xv), z1));         \
    z1 = fmaf(cf.na2, yv, fmaf(cf.b2, (xv), z2));         \
    z2 = fmaf(cf.na3, yv, fmaf(cf.b3, (xv), z3));         \
    z3 = fmaf(cf.na4, yv, fmaf(cf.b4, (xv), z4));         \
    z4 = fmaf(cf.na5, yv, fmaf(cf.b5, (xv), z5));         \
    z5 = fmaf(cf.na6, yv, fmaf(cf.b6, (xv), z6));         \
    z6 = fmaf(cf.na7, yv, fmaf(cf.b7, (xv), z7));         \
    z7 = fmaf(cf.na8, yv, cf.b8 * (xv));                  \
  } while (0)

#define ZINIT(v)                                          \
  do {                                                    \
    z0 = cf.zi0 * (v); z1 = cf.zi1 * (v);                 \
    z2 = cf.zi2 * (v); z3 = cf.zi3 * (v);                 \
    z4 = cf.zi4 * (v); z5 = cf.zi5 * (v);                 \
    z6 = cf.zi6 * (v); z7 = cf.zi7 * (v);                 \
  } while (0)

__device__ __forceinline__ void load_win(const float* __restrict__ p, int base,
                                         float4 (&W)[16]) {
#pragma unroll
  for (int q = 0; q < 16; ++q)
    W[q] = *reinterpret_cast<const float4*>(p + base + 4 * q);
}

__device__ __forceinline__ float xext(const float* __restrict__ rx, int vt) {
  if (vt < 0) return 2.0f * rx[0] - rx[-vt];
  if (vt >= TLEN) return 2.0f * rx[TLEN - 1] - rx[2 * TLEN - 2 - vt];
  return rx[vt];
}

__device__ __forceinline__ void load_win_edge(const float* __restrict__ rx, int vt0,
                                              float4 (&W)[16]) {
#pragma unroll
  for (int q = 0; q < 16; ++q) {
    W[q].x = xext(rx, vt0 + 4 * q + 0);
    W[q].y = xext(rx, vt0 + 4 * q + 1);
    W[q].z = xext(rx, vt0 + 4 * q + 2);
    W[q].w = xext(rx, vt0 + 4 * q + 3);
  }
}

// =============== K1: forward scan, in-register windows, row-major ============
// Wave-job = (chunk c 0..127, ch-group). Chunk c owns e in [512c, 512c+511]
// (c=127: ..65589).  Warm 253 from e_s = 512c-253 (== 3 mod 4); c==0 exact zi
// with 3-step scalar head (e=0..2), rounds from e=3.  Stores carry-packed
// float4 quads [e-3..e] fired at e == 3 mod 4, predicated to own range.
__global__ __launch_bounds__(64) void k_fwd3(const float* __restrict__ x,
                                             float* __restrict__ yb, Coefs cf) {
  const int job = blockIdx.x;                  // 0..1023
  const int c = job & 127;
  const int m = (job >> 7) * 64 + threadIdx.x; // channel
  const float* rx = x + (size_t)m * TLEN;
  float* ry = yb + (size_t)m * YPITCH;
  float z0, z1, z2, z3, z4, z5, z6, z7;
  float4 oq = make_float4(0.f, 0.f, 0.f, 0.f);
  int e_s, R;
  if (c == 0) {
    float x0 = 2.0f * rx[0] - rx[27];          // x_ext(0)
    ZINIT(x0);
    float yv;
    IIR_STEP(x0, yv); oq.x = yv;               // e=0
    float x1 = 2.0f * rx[0] - rx[26];
    IIR_STEP(x1, yv); oq.y = yv;               // e=1
    float x2 = 2.0f * rx[0] - rx[25];
    IIR_STEP(x2, yv); oq.z = yv;               // e=2
    e_s = 3; R = 8;
  } else {
    e_s = 512 * c - 253;                       // == 3 mod 4
    R = (c == 127) ? 13 : 12;
    float x0 = rx[e_s - 27];                   // vt >= 232: interior
    ZINIT(x0);
  }
  const int own_lo = 512 * c;
  const int own_qhi = (c == 127) ? 65588 : 512 * c + 508;   // last quad base
  float4 W[16], Wn[16];
  if (c == 0) load_win_edge(rx, e_s - 27, W);  // vt in [-24,39]
  else load_win(rx, e_s - 27, W);
  for (int r = 0; r < R; ++r) {
    if (r + 1 < R) {
      const int vtn = e_s - 27 + 64 * (r + 1);
      if (c == 127 && r + 1 == 12) load_win_edge(rx, vtn, Wn);  // vt >= 65512
      else load_win(rx, vtn, Wn);
    }
    const int ebase = e_s + 64 * r;            // == 3 mod 4
#pragma unroll
    for (int q = 0; q < 16; ++q) {
      float yv;
      IIR_STEP(W[q].x, yv); oq.w = yv;         // e = ebase+4q == 3 mod 4
      {
        const int sb = ebase + 4 * q - 3;      // quad base
        if (sb >= own_lo && sb <= own_qhi)
          *reinterpret_cast<float4*>(ry + sb) = oq;
      }
      IIR_STEP(W[q].y, yv); oq.x = yv;         // e == 0 mod 4
      IIR_STEP(W[q].z, yv); oq.y = yv;
      IIR_STEP(W[q].w, yv); oq.z = yv;
    }
#pragma unroll
    for (int q = 0; q < 16; ++q) W[q] = Wn[q];
  }
}

// =============== K2: backward scan + decimate, in-register windows ===========
// Reversed scan over e descending.  Chunk c owns output quads n in
// [128c, 128c+124] (n = (e-27)/4, e == 3 mod 4).  Warm 256 from
// e_top = 512c+791 (== 3 mod 4, == 7 mod 16); c==127 exact zi at e=65589
// with 14-step scalar head, rounds from 65575.  Output packed descending
// (.w,.z,.y,.x), float4 store at out[m][n] when quad completes.
__global__ __launch_bounds__(64) void k_bwd3(const float* __restrict__ yb,
                                             float* __restrict__ out, Coefs cf) {
  const int job = blockIdx.x;
  const int c = job & 127;
  const int m = (job >> 7) * 64 + threadIdx.x;
  const float* ry = yb + (size_t)m * YPITCH;
  float* ro = out + (size_t)m * 16384;
  float z0, z1, z2, z3, z4, z5, z6, z7;
  float4 pk = make_float4(0.f, 0.f, 0.f, 0.f);
  int e_top, R;
  if (c == 127) {
    float y0 = ry[65589];
    ZINIT(y0);                                 // exact: zi * y(last)
    float wv;
#pragma unroll
    for (int s = 0; s < 14; ++s) {             // e = 65589..65576, no outputs kept
      float yin = ry[65589 - s];
      IIR_STEP(yin, wv);
      (void)wv;
    }
    e_top = 65575; R = 9;                      // 65575 == 7 mod 16
  } else {
    const int e_b = 512 * c + 791;             // == 7 mod 16
    float y0 = ry[e_b];
    ZINIT(y0);
    e_top = e_b; R = 12;
  }
  const int n_lo = 128 * c, n_hi = 128 * c + 124;
  float4 W[16], Wn[16];
  load_win(ry, e_top - 63, W);
  for (int r = 0; r < R; ++r) {
    if (r + 1 < R) load_win(ry, e_top - 63 - 64 * (r + 1), Wn);
    const int elo = e_top - 63 - 64 * r;       // == 0 mod 4, == 8 mod 16
    const int nb = (elo - 24) >> 2;            // n of quad q = nb + q
#pragma unroll
    for (int q = 15; q >= 0; --q) {            // e descending
      float wv;
      IIR_STEP(W[q].w, wv);                    // e = elo+4q+3 == 3 mod 4: output
      const int ph = q & 3;                    // n & 3 == q & 3
      if (ph == 3) pk.w = wv;
      else if (ph == 2) pk.z = wv;
      else if (ph == 1) pk.y = wv;
      else {
        pk.x = wv;
        const int n = nb + q;
        if (n >= n_lo && n <= n_hi)
          *reinterpret_cast<float4*>(ro + n) = pk;
      }
      IIR_STEP(W[q].z, wv);
      IIR_STEP(W[q].y, wv);
      IIR_STEP(W[q].x, wv);
      (void)wv;
    }
#pragma unroll
    for (int q = 0; q < 16; ++q) W[q] = Wn[q];
  }
}

// ---------------- host: exact cheby1/zi design in double ----------------------
static void solve8(double Mm[8][9], double* zi) {
  for (int col = 0; col < 8; ++col) {
    int piv = col;
    for (int r = col + 1; r < 8; ++r)
      if (std::fabs(Mm[r][col]) > std::fabs(Mm[piv][col])) piv = r;
    if (piv != col)
      for (int j = 0; j < 9; ++j) { double t = Mm[col][j]; Mm[col][j] = Mm[piv][j]; Mm[piv][j] = t; }
    double d = Mm[col][col];
    for (int j = col; j < 9; ++j) Mm[col][j] /= d;
    for (int r = 0; r < 8; ++r)
      if (r != col) {
        double f = Mm[r][col];
        if (f != 0.0)
          for (int j = col; j < 9; ++j) Mm[r][j] -= f * Mm[col][j];
      }
  }
  for (int i = 0; i < 8; ++i) zi[i] = Mm[i][8];
}

static Coefs make_coefs() {
  using cd = std::complex<double>;
  const int N = 8;
  const double rp = 0.05, Wn = 0.8 / 4.0;
  double eps = std::sqrt(std::pow(10.0, 0.1 * rp) - 1.0);
  double mu = std::asinh(1.0 / eps) / N;
  cd p[8];
  for (int i = 0; i < N; ++i) {
    double th = M_PI * (2.0 * (i + 1) - 1.0) / (2.0 * N);
    p[i] = cd(-std::sinh(mu) * std::sin(th), std::cosh(mu) * std::cos(th));
  }
  cd pr(1.0, 0.0);
  for (int i = 0; i < N; ++i) pr *= -p[i];
  double g = pr.real();
  g /= std::sqrt(1.0 + eps * eps);                 // N even
  const double fs = 2.0;
  double warped = 2.0 * fs * std::tan(M_PI * Wn / fs);
  for (int i = 0; i < N; ++i) p[i] *= warped;
  g *= std::pow(warped, (double)N);
  const double fs2 = 2.0 * fs;
  cd pd[8], dpr(1.0, 0.0);
  for (int i = 0; i < N; ++i) {
    pd[i] = (cd(fs2, 0.0) + p[i]) / (cd(fs2, 0.0) - p[i]);
    dpr *= (cd(fs2, 0.0) - p[i]);
  }
  double gd = g * (cd(1.0, 0.0) / dpr).real();
  static const double binom[9] = {1, 8, 28, 56, 70, 56, 28, 8, 1};
  double b[9], a[9];
  for (int i = 0; i < 9; ++i) b[i] = gd * binom[i];
  cd cp[9]; cp[0] = cd(1, 0);
  for (int i = 1; i < 9; ++i) cp[i] = cd(0, 0);
  for (int i = 0; i < N; ++i)
    for (int j = i + 1; j >= 1; --j) cp[j] -= pd[i] * cp[j - 1];
  for (int i = 0; i < 9; ++i) a[i] = cp[i].real();
  double Mm[8][9];
  for (int i = 0; i < 8; ++i) {
    for (int j = 0; j < 9; ++j) Mm[i][j] = 0.0;
    Mm[i][0] += a[i + 1];
    Mm[i][i] += 1.0;
    if (i < 7) Mm[i][i + 1] = -1.0;
    Mm[i][8] = b[i + 1] - a[i + 1] * b[0];
  }
  double zi[8];
  solve8(Mm, zi);
  Coefs cf;
  cf.b0 = (float)b[0]; cf.b1 = (float)b[1]; cf.b2 = (float)b[2]; cf.b3 = (float)b[3];
  cf.b4 = (float)b[4]; cf.b5 = (float)b[5]; cf.b6 = (float)b[6]; cf.b7 = (float)b[7];
  cf.b8 = (float)b[8];
  cf.na1 = (float)(-a[1]); cf.na2 = (float)(-a[2]); cf.na3 = (float)(-a[3]);
  cf.na4 = (float)(-a[4]); cf.na5 = (float)(-a[5]); cf.na6 = (float)(-a[6]);
  cf.na7 = (float)(-a[7]); cf.na8 = (float)(-a[8]);
  cf.zi0 = (float)zi[0]; cf.zi1 = (float)zi[1]; cf.zi2 = (float)zi[2]; cf.zi3 = (float)zi[3];
  cf.zi4 = (float)zi[4]; cf.zi5 = (float)zi[5]; cf.zi6 = (float)zi[6]; cf.zi7 = (float)zi[7];
  return cf;
}

}  // namespace

extern "C" void kernel_launch(void* const* d_in, const int* in_sizes, int n_in,
                              void* d_out, int out_size, void* d_ws, size_t ws_size,
                              hipStream_t stream) {
  (void)in_sizes; (void)n_in; (void)out_size; (void)ws_size;
  const float* x = (const float*)d_in[0];
  float* out = (float*)d_out;
  float* yb  = (float*)d_ws;                       // 512 x 65600 x 4B = 134.3 MB
  Coefs cf = make_coefs();                         // pure host math, capture-safe
  hipLaunchKernelGGL(k_fwd3, dim3(1024), dim3(64), 0, stream, x, yb, cf);
  hipLaunchKernelGGL(k_bwd3, dim3(1024), dim3(64), 0, stream, yb, out, cf);
}